// Round 1
// baseline (448.674 us; speedup 1.0000x reference)
//
#include <hip/hip_runtime.h>
#include <math.h>

typedef _Float16 f16;
typedef _Float16 half8 __attribute__((ext_vector_type(8)));
typedef _Float16 half4 __attribute__((ext_vector_type(4)));
typedef float float4v __attribute__((ext_vector_type(4)));
typedef int int4v __attribute__((ext_vector_type(4)));

#define MFMA16(a, b, c) __builtin_amdgcn_mfma_f32_16x16x32_f16((a), (b), (c), 0, 0, 0)

// problem: B=4096 L=32 V=50000 D=300 H=6 HD=50 ; K padded to 320
// Fragment-swizzled layout: element (n, k) of a [Nt*16][320] matrix lives at
//   F[((n>>4)*10 + (k>>5))*512 + (((k>>3)&3)*16 + (n&15))*8 + (k&7)]

// ---------------- ws layout (bytes) ----------------
#define WQKV_OFF 0u          // f16 frag-swizzled [64 ntiles] (q*rs | k | v rows, pads 0)
#define BQKV_OFF 655360u     // f32 [1024]
#define WO_OFF   659456u     // f16 frag-swizzled [20 ntiles] Wo
#define WVA_OFF  864256u     // f16 frag-swizzled [20 ntiles] Va@Wo
#define BVA_OFF  1069056u    // f32 [320]  Va@bo+ba (pads 0)
#define CBAR_OFF 1070336u    // f16 [4096][320] row-major
#define XF_OFF   3691776u    // f16 frag-swizzled x: per item 20 fragblks of 512

__device__ __forceinline__ float fast_tanh(float x) {
    float e = __expf(2.f * x);
    return 1.f - 2.f / (e + 1.f);
}

// ---------------- repack1: Wqkv + Wo -> frag-swizzled f16, bqkv ----------
__global__ void repack1(const float* __restrict__ Wq, const float* __restrict__ Wk,
                        const float* __restrict__ Wv, const float* __restrict__ Wo,
                        const float* __restrict__ bq, const float* __restrict__ bk,
                        const float* __restrict__ bv,
                        f16* __restrict__ wqkvF, f16* __restrict__ wo16F,
                        float* __restrict__ bqkv) {
    int idx = blockIdx.x * 256 + threadIdx.x;
    const float rs = 0.14142135623730951f;  // 1/sqrt(50)
    if (idx < 327680) {  // wqkvF: 64 ntiles
        int ntile = idx / 5120, rem = idx - ntile * 5120;
        int ks = rem / 512, r2 = rem - ks * 512;
        int lane = r2 >> 3, j = r2 & 7;
        int n = ntile * 16 + (lane & 15);
        int k = ks * 32 + (lane >> 4) * 8 + j;
        int g = n / 320, r = n - g * 320;
        float v = 0.f;
        if (r < 300 && k < 300) {
            if (g == 0) v = Wq[r * 300 + k] * rs;
            else if (g == 1) v = Wk[r * 300 + k];
            else if (g == 2) v = Wv[r * 300 + k];
        }
        wqkvF[idx] = (f16)v;
    } else if (idx < 430080) {  // wo16F: 20 ntiles
        int t = idx - 327680;
        int ntile = t / 5120, rem = t - ntile * 5120;
        int ks = rem / 512, r2 = rem - ks * 512;
        int lane = r2 >> 3, j = r2 & 7;
        int n = ntile * 16 + (lane & 15);
        int k = ks * 32 + (lane >> 4) * 8 + j;
        wo16F[t] = (f16)((n < 300 && k < 300) ? Wo[n * 300 + k] : 0.f);
    } else if (idx < 431104) {  // bqkv [1024]
        int n = idx - 430080;
        int g = n / 320, r = n - g * 320;
        float v = 0.f;
        if (r < 300) {
            if (g == 0) v = bq[r] * rs;
            else if (g == 1) v = bk[r];
            else if (g == 2) v = bv[r];
        }
        bqkv[n] = v;
    }
}

// ---------------- repack2: Wva = Va @ Wo -> frag-swizzled ----------------
__global__ void repack2(const float* __restrict__ Va, const float* __restrict__ Wo,
                        f16* __restrict__ wvaF) {
    int bt = blockIdx.x;  // 400 = 20*20
    int mt = bt / 20, nt = bt % 20;
    int lane = threadIdx.x & 63;
    int lr = lane & 15, quad = lane >> 4;
    float4v acc = {0.f, 0.f, 0.f, 0.f};
    int m = mt * 16 + lr;   // Wva row
    int nn = nt * 16 + lr;  // Wva col (= Wo output dim)
    for (int ks = 0; ks < 10; ++ks) {
        int c = ks * 32 + quad * 8;
        half8 af, bf;
#pragma unroll
        for (int j = 0; j < 8; ++j) {
            int cc = c + j;
            af[j] = (f16)((m < 300 && cc < 300) ? Va[m * 300 + cc] : 0.f);
            bf[j] = (f16)((nn < 300 && cc < 300) ? Wo[cc * 300 + nn] : 0.f);
        }
        acc = MFMA16(af, bf, acc);
    }
#pragma unroll
    for (int r = 0; r < 4; ++r) {
        int row = mt * 16 + quad * 4 + r;  // Wva row index (n of va GEMM)
        int col = nt * 16 + lr;            // Wva col index (k of va GEMM)
        int addr = ((row >> 4) * 10 + (col >> 5)) * 512 +
                   (((col >> 3) & 3) * 16 + (row & 15)) * 8 + (col & 7);
        wvaF[addr] = (f16)acc[r];
    }
}

// ---------------- repack3: bva = Va @ bo + ba ----------------
__global__ void repack3(const float* __restrict__ Va, const float* __restrict__ bo,
                        const float* __restrict__ ba, float* __restrict__ bva) {
    int j = threadIdx.x;  // 320
    float s = 0.f;
    if (j < 300) {
        for (int k = 0; k < 300; ++k) s += Va[j * 300 + k] * bo[k];
        s += ba[j];
    }
    bva[j] = s;
}

// ---------------- gather: x = emb[title] + pos, frag-swizzled ------------
__global__ void gather_kernel(const int* __restrict__ title, const float* __restrict__ emb,
                              const float* __restrict__ pos, f16* __restrict__ xF) {
    int c = blockIdx.x * 256 + threadIdx.x;  // < 131072*40
    int fragblk = c >> 6, lane = c & 63;
    int item = fragblk / 20, rem = fragblk - item * 20;
    int mt = rem / 10, ks = rem - mt * 10;
    int lr = lane & 15, quad = lane >> 4;
    int row = item * 32 + mt * 16 + lr;
    int col = ks * 32 + quad * 8;
    int t = title[row];
    int l = row & 31;
    half8 h;
    if (col + 8 <= 300) {
        float4v e0 = *(const float4v*)&emb[t * 300 + col];
        float4v e1 = *(const float4v*)&emb[t * 300 + col + 4];
        float4v p0 = *(const float4v*)&pos[l * 300 + col];
        float4v p1 = *(const float4v*)&pos[l * 300 + col + 4];
#pragma unroll
        for (int j = 0; j < 4; ++j) { h[j] = (f16)(e0[j] + p0[j]); h[4 + j] = (f16)(e1[j] + p1[j]); }
    } else {
#pragma unroll
        for (int j = 0; j < 8; ++j) {
            int cc = col + j;
            h[j] = (f16)((cc < 300) ? emb[t * 300 + cc] + pos[l * 300 + cc] : 0.f);
        }
    }
    *(half8*)&xF[c * 8] = h;
}

// ---- fused QKV GEMM + attention + va + softmax + pool: 1 item/block ----
// LDS: qL/kL [6*32][72], vT [6*64][32] (XOR-swizzled) + aL/alpha = 80,128 B
// -> 2 blocks/CU (16 waves), two independent barrier domains overlap phases.
__global__ __launch_bounds__(512, 4) void qkvattn_kernel(
    const f16* __restrict__ xF, const f16* __restrict__ wqkvF,
    const float* __restrict__ bqkv, const f16* __restrict__ wvaF,
    const float* __restrict__ bva, const float* __restrict__ qw,
    f16* __restrict__ cbar) {
    __shared__ __align__(16) f16 qL[6 * 32 * 72];
    __shared__ __align__(16) f16 kL[6 * 32 * 72];
    __shared__ __align__(16) f16 vT[6 * 64 * 32];
    __shared__ float aL[32];
    __shared__ float alpha[32];
    const int ib = blockIdx.x, tid = threadIdx.x;
    const int w = tid >> 6, lane = tid & 63, lr = lane & 15, quad = lane >> 4;
    const float4v vz = {0.f, 0.f, 0.f, 0.f};
    const int4v z4 = {0, 0, 0, 0};

    // zero q/k/v staging (pads must be 0) and aL — wide 16B stores
    {
        int4v* q4 = (int4v*)qL;  // 27648 B = 1728
        int4v* k4 = (int4v*)kL;
        int4v* v4 = (int4v*)vT;  // 24576 B = 1536
        for (int i = tid; i < 1728; i += 512) { q4[i] = z4; k4[i] = z4; }
        for (int i = tid; i < 1536; i += 512) v4[i] = z4;
        if (tid < 32) aL[tid] = 0.f;
    }
    __syncthreads();

    // --- Phase 1: QKV GEMM, M=32 (item ib), N=960 (60 real tiles), K=320 ---
    {
        float4v acc[2][8];
#pragma unroll
        for (int mt = 0; mt < 2; ++mt)
#pragma unroll
            for (int j = 0; j < 8; ++j) acc[mt][j] = vz;
        for (int ks = 0; ks < 10; ++ks) {
            half8 a0 = *(const half8*)&xF[(((ib * 2 + 0) * 10 + ks) * 64 + lane) * 8];
            half8 a1 = *(const half8*)&xF[(((ib * 2 + 1) * 10 + ks) * 64 + lane) * 8];
#pragma unroll
            for (int j = 0; j < 8; ++j) {
                int tile = w * 8 + j;
                if (tile < 60) {  // skip pure-pad tiles 60..63 (wave-uniform)
                    half8 bf = *(const half8*)&wqkvF[((tile * 10 + ks) * 64 + lane) * 8];
                    acc[0][j] = MFMA16(a0, bf, acc[0][j]);
                    acc[1][j] = MFMA16(a1, bf, acc[1][j]);
                }
            }
        }
        // epilogue: scatter q/k/v into LDS (wi is wave-uniform per j: 8 | 20)
#pragma unroll
        for (int j = 0; j < 8; ++j) {
            int tile = w * 8 + j;
            int wi = tile / 20;
            int n = tile * 16 + lr;
            int cc = n - wi * 320;
            if (wi < 3 && cc < 300) {
                float bb = bqkv[n];
                int h = cc / 50, d = cc - h * 50;
                if (wi == 2) {  // v: packed b64 write, XOR-swizzled on byte bits 4-5
#pragma unroll
                    for (int mt = 0; mt < 2; ++mt) {
                        int row0 = mt * 16 + quad * 4;
                        half4 pk;
#pragma unroll
                        for (int r = 0; r < 4; ++r) pk[r] = (f16)(acc[mt][j][r] + bb);
                        int idx = (h * 64 + d) * 32 + row0;
                        int byt = (idx * 2) ^ (((d >> 2) & 3) << 4);
                        *(half4*)((char*)vT + byt) = pk;
                    }
                } else {
                    f16* dst = (wi == 0) ? qL : kL;
#pragma unroll
                    for (int mt = 0; mt < 2; ++mt)
#pragma unroll
                        for (int r = 0; r < 4; ++r) {
                            int row = mt * 16 + quad * 4 + r;
                            dst[(h * 32 + row) * 72 + d] = (f16)(acc[mt][j][r] + bb);
                        }
                }
            }
        }
    }
    __syncthreads();

    // --- Phase 2: wave hh (<6) computes scores + softmax -> P (aliases qL) ---
    const int hh = w;
    if (w < 6) {
        float4v s00 = vz, s01 = vz, s10 = vz, s11 = vz;
#pragma unroll
        for (int ks = 0; ks < 2; ++ks) {
            int c = ks * 32 + quad * 8;
            half8 aq0 = *(const half8*)&qL[(hh * 32 + lr) * 72 + c];
            half8 aq1 = *(const half8*)&qL[(hh * 32 + 16 + lr) * 72 + c];
            half8 bk0 = *(const half8*)&kL[(hh * 32 + lr) * 72 + c];
            half8 bk1 = *(const half8*)&kL[(hh * 32 + 16 + lr) * 72 + c];
            s00 = MFMA16(aq0, bk0, s00);
            s01 = MFMA16(aq0, bk1, s01);
            s10 = MFMA16(aq1, bk0, s10);
            s11 = MFMA16(aq1, bk1, s11);
        }
        f16* ph = qL + hh * 32 * 72;
#pragma unroll
        for (int mt = 0; mt < 2; ++mt) {
            float4v sv0 = mt ? s10 : s00;
            float4v sv1 = mt ? s11 : s01;
#pragma unroll
            for (int r = 0; r < 4; ++r) {
                float v0 = sv0[r], v1 = sv1[r];
                float m = fmaxf(v0, v1);
#pragma unroll
                for (int off = 1; off < 16; off <<= 1) m = fmaxf(m, __shfl_xor(m, off, 64));
                float e0 = __expf(v0 - m), e1 = __expf(v1 - m);
                float ss = e0 + e1;
#pragma unroll
                for (int off = 1; off < 16; off <<= 1) ss += __shfl_xor(ss, off, 64);
                float inv = 1.0f / ss;
                int row = mt * 16 + quad * 4 + r;
                ph[row * 40 + lr] = (f16)(e0 * inv);
                ph[row * 40 + 16 + lr] = (f16)(e1 * inv);
            }
        }
    }
    __syncthreads();

    // --- Phase 3: ctx = P @ V -> row-major scratch (reuses kL, [32][328]) ---
    f16* scratch = kL;
    for (int i = tid; i < 32 * 28; i += 512) {  // zero pad cols 300..327
        int row = i / 28, cc = 300 + (i - row * 28);
        scratch[row * 328 + cc] = (f16)0.f;
    }
    if (w < 6) {
        int h = hh;
        f16* ph = qL + hh * 32 * 72;
        half8 aw0 = *(const half8*)&ph[lr * 40 + quad * 8];
        half8 aw1 = *(const half8*)&ph[(16 + lr) * 40 + quad * 8];
        float4v c0[4], c1[4];
#pragma unroll
        for (int nt = 0; nt < 4; ++nt) { c0[nt] = vz; c1[nt] = vz; }
#pragma unroll
        for (int nt = 0; nt < 4; ++nt) {
            int rIdx = nt * 16 + lr;
            int idx = (hh * 64 + rIdx) * 32 + quad * 8;
            int byt = (idx * 2) ^ (((rIdx >> 2) & 3) << 4);
            half8 bvf = *(const half8*)((const char*)vT + byt);
            c0[nt] = MFMA16(aw0, bvf, c0[nt]);
            c1[nt] = MFMA16(aw1, bvf, c1[nt]);
        }
#pragma unroll
        for (int mt = 0; mt < 2; ++mt)
#pragma unroll
            for (int nt = 0; nt < 4; ++nt)
#pragma unroll
                for (int r = 0; r < 4; ++r) {
                    int d = nt * 16 + lr;
                    if (d < 50) {
                        int row = mt * 16 + quad * 4 + r;
                        float4v cv = mt ? c1[nt] : c0[nt];
                        scratch[row * 328 + h * 50 + d] = (f16)cv[r];
                    }
                }
    }
    __syncthreads();

    // --- Phase 4: va GEMM from scratch: y = ctx @ Wva^T + bva; a[l] = sum tanh(y)*qw ---
    {
        const int mtile = w >> 2, nsub = w & 3;  // 2 m-tiles x 4 n-groups, 5 ntiles each
        float4v vacc[5];
#pragma unroll
        for (int i = 0; i < 5; ++i) vacc[i] = vz;
        const int arow = (mtile * 16 + lr) * 328;
        for (int ks = 0; ks < 10; ++ks) {
            half8 a = *(const half8*)&scratch[arow + ks * 32 + quad * 8];
#pragma unroll
            for (int i = 0; i < 5; ++i) {
                half8 bf = *(const half8*)&wvaF[((((nsub * 5 + i) * 10) + ks) * 64 + lane) * 8];
                vacc[i] = MFMA16(a, bf, vacc[i]);
            }
        }
        float ps[4] = {0.f, 0.f, 0.f, 0.f};
#pragma unroll
        for (int i = 0; i < 5; ++i) {
            int n = (nsub * 5 + i) * 16 + lr;
            float bb = bva[n];
            float qq = (n < 300) ? qw[n] : 0.f;
#pragma unroll
            for (int r = 0; r < 4; ++r) ps[r] += fast_tanh(vacc[i][r] + bb) * qq;
        }
#pragma unroll
        for (int r = 0; r < 4; ++r)
#pragma unroll
            for (int off = 1; off < 16; off <<= 1) ps[r] += __shfl_xor(ps[r], off, 64);
        if (lr == 0) {
#pragma unroll
            for (int r = 0; r < 4; ++r) atomicAdd(&aL[mtile * 16 + quad * 4 + r], ps[r]);
        }
    }
    __syncthreads();

    // --- Phase 5: one 32-row softmax (lanes 0-31 of wave 0) ---
    if (w == 0 && lane < 32) {
        float av = aL[lane];
        float m = av;
#pragma unroll
        for (int off = 1; off < 32; off <<= 1) m = fmaxf(m, __shfl_xor(m, off, 32));
        float e = __expf(av - m);
        float ss = e;
#pragma unroll
        for (int off = 1; off < 32; off <<= 1) ss += __shfl_xor(ss, off, 32);
        alpha[lane] = e / ss;
    }
    __syncthreads();

    // --- Phase 6: cbar[ib][d] = sum_l alpha[l] * ctx[l][d] ---
    if (tid < 320) {
        int d = tid;
        float acc = 0.f;
#pragma unroll
        for (int l = 0; l < 32; ++l)
            acc += alpha[l] * (float)scratch[l * 328 + d];
        cbar[ib * 320 + d] = (f16)acc;
    }
}

// ---------------- out = cbar @ Wo^T + bo, f32 [4096][300] ----------------
__global__ __launch_bounds__(512) void out_kernel(
    const f16* __restrict__ cbar, const f16* __restrict__ wo16F,
    const float* __restrict__ bo, float* __restrict__ out) {
    __shared__ __align__(16) f16 cA[32 * 328];
    const int mb = blockIdx.x, tid = threadIdx.x;  // 128 blocks, M=32
    const int w = tid >> 6, lane = tid & 63, lr = lane & 15, quad = lane >> 4;
    const int mh = w >> 2, nsub = w & 3;
    for (int i = tid; i < 1280; i += 512) {
        int row = i / 40, g = i - row * 40;
        *(half8*)&cA[row * 328 + g * 8] = *(const half8*)&cbar[(mb * 32 + row) * 320 + g * 8];
    }
    __syncthreads();
    const float4v vz = {0.f, 0.f, 0.f, 0.f};
    float4v acc[5];
#pragma unroll
    for (int i = 0; i < 5; ++i) acc[i] = vz;
    for (int ks = 0; ks < 10; ++ks) {
        half8 a = *(const half8*)&cA[(mh * 16 + lr) * 328 + ks * 32 + quad * 8];
#pragma unroll
        for (int i = 0; i < 5; ++i) {
            half8 bf = *(const half8*)&wo16F[((((nsub * 5 + i) * 10) + ks) * 64 + lane) * 8];
            acc[i] = MFMA16(a, bf, acc[i]);
        }
    }
#pragma unroll
    for (int i = 0; i < 5; ++i) {
        int n = (nsub * 5 + i) * 16 + lr;
        if (n < 300) {
            float bb = bo[n];
#pragma unroll
            for (int r = 0; r < 4; ++r)
                out[(mb * 32 + mh * 16 + quad * 4 + r) * 300 + n] = acc[i][r] + bb;
        }
    }
}

// ---------------- host launcher ----------------
extern "C" void kernel_launch(void* const* d_in, const int* in_sizes, int n_in,
                              void* d_out, int out_size, void* d_ws, size_t ws_size,
                              hipStream_t stream) {
    const int* title = (const int*)d_in[0];
    const float* emb = (const float*)d_in[1];
    const float* pos = (const float*)d_in[2];
    const float* Wq = (const float*)d_in[3];
    const float* bq = (const float*)d_in[4];
    const float* Wk = (const float*)d_in[5];
    const float* bk = (const float*)d_in[6];
    const float* Wv = (const float*)d_in[7];
    const float* bv = (const float*)d_in[8];
    const float* Wo = (const float*)d_in[9];
    const float* bo = (const float*)d_in[10];
    const float* Va = (const float*)d_in[11];
    const float* ba = (const float*)d_in[12];
    const float* qw = (const float*)d_in[13];
    char* ws = (char*)d_ws;
    float* out = (float*)d_out;

    f16* wqkvF = (f16*)(ws + WQKV_OFF);
    float* bqkv = (float*)(ws + BQKV_OFF);
    f16* wo16F = (f16*)(ws + WO_OFF);
    f16* wvaF = (f16*)(ws + WVA_OFF);
    float* bva = (float*)(ws + BVA_OFF);
    f16* cbar = (f16*)(ws + CBAR_OFF);
    f16* xF = (f16*)(ws + XF_OFF);

    repack1<<<1684, 256, 0, stream>>>(Wq, Wk, Wv, Wo, bq, bk, bv, wqkvF, wo16F, bqkv);
    repack2<<<400, 64, 0, stream>>>(Va, Wo, wvaF);
    repack3<<<1, 320, 0, stream>>>(Va, bo, ba, bva);
    gather_kernel<<<20480, 256, 0, stream>>>(title, emb, pos, xF);
    qkvattn_kernel<<<4096, 512, 0, stream>>>(xF, wqkvF, bqkv, wvaF, bva, qw, cbar);
    out_kernel<<<128, 512, 0, stream>>>(cbar, wo16F, bo, out);
}

// Round 2
// 446.389 us; speedup vs baseline: 1.0051x; 1.0051x over previous
//
#include <hip/hip_runtime.h>
#include <math.h>

typedef _Float16 f16;
typedef _Float16 half8 __attribute__((ext_vector_type(8)));
typedef _Float16 half4 __attribute__((ext_vector_type(4)));
typedef float float4v __attribute__((ext_vector_type(4)));
typedef int int4v __attribute__((ext_vector_type(4)));

#define MFMA16(a, b, c) __builtin_amdgcn_mfma_f32_16x16x32_f16((a), (b), (c), 0, 0, 0)

// problem: B=4096 L=32 V=50000 D=300 H=6 HD=50 ; K padded to 320
// Fragment-swizzled layout: element (n, k) of a [Nt*16][320] matrix lives at
//   F[((n>>4)*10 + (k>>5))*512 + (((k>>3)&3)*16 + (n&15))*8 + (k&7)]

// ---------------- ws layout (bytes) ----------------
#define WQKV_OFF 0u          // f16 frag-swizzled [64 ntiles] (q*rs | k | v rows, pads 0)
#define BQKV_OFF 655360u     // f32 [1024]
#define WO_OFF   659456u     // f16 frag-swizzled [20 ntiles] Wo
#define WVA_OFF  864256u     // f16 frag-swizzled [20 ntiles] Va@Wo
#define BVA_OFF  1069056u    // f32 [320]  Va@bo+ba (pads 0)
#define CBAR_OFF 1070336u    // f16 [4096][320] row-major
#define XF_OFF   3691776u    // f16 frag-swizzled x: per item 20 fragblks of 512

__device__ __forceinline__ float fast_tanh(float x) {
    float e = __expf(2.f * x);
    return 1.f - 2.f / (e + 1.f);
}

// ---------------- repack1: Wqkv + Wo -> frag-swizzled f16, bqkv ----------
__global__ void repack1(const float* __restrict__ Wq, const float* __restrict__ Wk,
                        const float* __restrict__ Wv, const float* __restrict__ Wo,
                        const float* __restrict__ bq, const float* __restrict__ bk,
                        const float* __restrict__ bv,
                        f16* __restrict__ wqkvF, f16* __restrict__ wo16F,
                        float* __restrict__ bqkv) {
    int idx = blockIdx.x * 256 + threadIdx.x;
    const float rs = 0.14142135623730951f;  // 1/sqrt(50)
    if (idx < 327680) {  // wqkvF: 64 ntiles
        int ntile = idx / 5120, rem = idx - ntile * 5120;
        int ks = rem / 512, r2 = rem - ks * 512;
        int lane = r2 >> 3, j = r2 & 7;
        int n = ntile * 16 + (lane & 15);
        int k = ks * 32 + (lane >> 4) * 8 + j;
        int g = n / 320, r = n - g * 320;
        float v = 0.f;
        if (r < 300 && k < 300) {
            if (g == 0) v = Wq[r * 300 + k] * rs;
            else if (g == 1) v = Wk[r * 300 + k];
            else if (g == 2) v = Wv[r * 300 + k];
        }
        wqkvF[idx] = (f16)v;
    } else if (idx < 430080) {  // wo16F: 20 ntiles
        int t = idx - 327680;
        int ntile = t / 5120, rem = t - ntile * 5120;
        int ks = rem / 512, r2 = rem - ks * 512;
        int lane = r2 >> 3, j = r2 & 7;
        int n = ntile * 16 + (lane & 15);
        int k = ks * 32 + (lane >> 4) * 8 + j;
        wo16F[t] = (f16)((n < 300 && k < 300) ? Wo[n * 300 + k] : 0.f);
    } else if (idx < 431104) {  // bqkv [1024]
        int n = idx - 430080;
        int g = n / 320, r = n - g * 320;
        float v = 0.f;
        if (r < 300) {
            if (g == 0) v = bq[r] * rs;
            else if (g == 1) v = bk[r];
            else if (g == 2) v = bv[r];
        }
        bqkv[n] = v;
    }
}

// ---------------- repack2: Wva = Va @ Wo -> frag-swizzled ----------------
__global__ void repack2(const float* __restrict__ Va, const float* __restrict__ Wo,
                        f16* __restrict__ wvaF) {
    int bt = blockIdx.x;  // 400 = 20*20
    int mt = bt / 20, nt = bt % 20;
    int lane = threadIdx.x & 63;
    int lr = lane & 15, quad = lane >> 4;
    float4v acc = {0.f, 0.f, 0.f, 0.f};
    int m = mt * 16 + lr;   // Wva row
    int nn = nt * 16 + lr;  // Wva col (= Wo output dim)
    for (int ks = 0; ks < 10; ++ks) {
        int c = ks * 32 + quad * 8;
        half8 af, bf;
#pragma unroll
        for (int j = 0; j < 8; ++j) {
            int cc = c + j;
            af[j] = (f16)((m < 300 && cc < 300) ? Va[m * 300 + cc] : 0.f);
            bf[j] = (f16)((nn < 300 && cc < 300) ? Wo[cc * 300 + nn] : 0.f);
        }
        acc = MFMA16(af, bf, acc);
    }
#pragma unroll
    for (int r = 0; r < 4; ++r) {
        int row = mt * 16 + quad * 4 + r;  // Wva row index (n of va GEMM)
        int col = nt * 16 + lr;            // Wva col index (k of va GEMM)
        int addr = ((row >> 4) * 10 + (col >> 5)) * 512 +
                   (((col >> 3) & 3) * 16 + (row & 15)) * 8 + (col & 7);
        wvaF[addr] = (f16)acc[r];
    }
}

// ---------------- repack3: bva = Va @ bo + ba ----------------
__global__ void repack3(const float* __restrict__ Va, const float* __restrict__ bo,
                        const float* __restrict__ ba, float* __restrict__ bva) {
    int j = threadIdx.x;  // 320
    float s = 0.f;
    if (j < 300) {
        for (int k = 0; k < 300; ++k) s += Va[j * 300 + k] * bo[k];
        s += ba[j];
    }
    bva[j] = s;
}

// ---------------- gather: x = emb[title] + pos, frag-swizzled ------------
__global__ void gather_kernel(const int* __restrict__ title, const float* __restrict__ emb,
                              const float* __restrict__ pos, f16* __restrict__ xF) {
    int c = blockIdx.x * 256 + threadIdx.x;  // < 131072*40
    int fragblk = c >> 6, lane = c & 63;
    int item = fragblk / 20, rem = fragblk - item * 20;
    int mt = rem / 10, ks = rem - mt * 10;
    int lr = lane & 15, quad = lane >> 4;
    int row = item * 32 + mt * 16 + lr;
    int col = ks * 32 + quad * 8;
    int t = title[row];
    int l = row & 31;
    half8 h;
    if (col + 8 <= 300) {
        float4v e0 = *(const float4v*)&emb[t * 300 + col];
        float4v e1 = *(const float4v*)&emb[t * 300 + col + 4];
        float4v p0 = *(const float4v*)&pos[l * 300 + col];
        float4v p1 = *(const float4v*)&pos[l * 300 + col + 4];
#pragma unroll
        for (int j = 0; j < 4; ++j) { h[j] = (f16)(e0[j] + p0[j]); h[4 + j] = (f16)(e1[j] + p1[j]); }
    } else {
#pragma unroll
        for (int j = 0; j < 8; ++j) {
            int cc = col + j;
            h[j] = (f16)((cc < 300) ? emb[t * 300 + cc] + pos[l * 300 + cc] : 0.f);
        }
    }
    *(half8*)&xF[c * 8] = h;
}

// ---- fused QKV GEMM + attention + va + softmax + pool: 1 item/block ----
// LDS: qL/kL [6*32][72], vT [6*64][32] (XOR-swizzled) = 80,064 B
// -> 2 blocks/CU. Critical-path trimmed: pad-only zeroing (no init barrier),
// fully unrolled k-loops, hoisted bias/B-frag loads, P5 fused into P6.
// Barriers: 4 (post-P1, post-P2, post-P3, post-P4).
__global__ __launch_bounds__(512, 4) void qkvattn_kernel(
    const f16* __restrict__ xF, const f16* __restrict__ wqkvF,
    const float* __restrict__ bqkv, const f16* __restrict__ wvaF,
    const float* __restrict__ bva, const float* __restrict__ qw,
    f16* __restrict__ cbar) {
    __shared__ __align__(16) f16 qL[6 * 32 * 72];
    __shared__ __align__(16) f16 kL[6 * 32 * 72];
    __shared__ __align__(16) f16 vT[6 * 64 * 32];
    __shared__ float aL[32];
    const int ib = blockIdx.x, tid = threadIdx.x;
    const int w = tid >> 6, lane = tid & 63, lr = lane & 15, quad = lane >> 4;
    const float4v vz = {0.f, 0.f, 0.f, 0.f};
    const int4v z4 = {0, 0, 0, 0};

    // --- pad-only zeroing: disjoint from P1 epilogue writes -> NO barrier here.
    // qL/kL: cols 50..63 of every (h,row) must be 0 (P2 reads c up to 63).
    for (int i = tid; i < 1344; i += 512) {  // 192 hrows x 7 dwords
        int hrow = i / 7, c = i - hrow * 7;
        ((int*)&qL[hrow * 72 + 50])[c] = 0;
        ((int*)&kL[hrow * 72 + 50])[c] = 0;
    }
    // vT: rows d=50..63 per head must be 0 (P3 nt=3 reads them). 84 rows x 64B.
    for (int i = tid; i < 336; i += 512) {
        int t = i >> 2, c4 = i & 3;
        int h = t / 14, d = 50 + (t - (t / 14) * 14);
        ((int4v*)&vT[(h * 64 + d) * 32])[c4] = z4;
    }
    if (tid < 32) aL[tid] = 0.f;  // visible at post-P1 barrier

    // --- Phase 1: QKV GEMM, M=32 (item ib), N=960 (60 real tiles), K=320 ---
    {
        float bb[8];
#pragma unroll
        for (int j = 0; j < 8; ++j) bb[j] = bqkv[(w * 8 + j) * 16 + lr];  // pads 0, hoisted
        float4v acc[2][8];
#pragma unroll
        for (int mt = 0; mt < 2; ++mt)
#pragma unroll
            for (int j = 0; j < 8; ++j) acc[mt][j] = vz;
#pragma unroll
        for (int ks = 0; ks < 10; ++ks) {
            half8 a0 = *(const half8*)&xF[(((ib * 2 + 0) * 10 + ks) * 64 + lane) * 8];
            half8 a1 = *(const half8*)&xF[(((ib * 2 + 1) * 10 + ks) * 64 + lane) * 8];
#pragma unroll
            for (int j = 0; j < 8; ++j) {
                int tile = w * 8 + j;
                if (tile < 60) {  // skip pure-pad tiles 60..63 (wave-uniform)
                    half8 bf = *(const half8*)&wqkvF[((tile * 10 + ks) * 64 + lane) * 8];
                    acc[0][j] = MFMA16(a0, bf, acc[0][j]);
                    acc[1][j] = MFMA16(a1, bf, acc[1][j]);
                }
            }
        }
        // epilogue: scatter q/k/v into LDS (wi is wave-uniform per j: 8 | 20)
#pragma unroll
        for (int j = 0; j < 8; ++j) {
            int tile = w * 8 + j;
            int wi = tile / 20;
            int n = tile * 16 + lr;
            int cc = n - wi * 320;
            if (wi < 3 && cc < 300) {
                int h = cc / 50, d = cc - h * 50;
                if (wi == 2) {  // v: packed b64 write, XOR-swizzled on byte bits 4-5
#pragma unroll
                    for (int mt = 0; mt < 2; ++mt) {
                        int row0 = mt * 16 + quad * 4;
                        half4 pk;
#pragma unroll
                        for (int r = 0; r < 4; ++r) pk[r] = (f16)(acc[mt][j][r] + bb[j]);
                        int idx = (h * 64 + d) * 32 + row0;
                        int byt = (idx * 2) ^ (((d >> 2) & 3) << 4);
                        *(half4*)((char*)vT + byt) = pk;
                    }
                } else {
                    f16* dst = (wi == 0) ? qL : kL;
#pragma unroll
                    for (int mt = 0; mt < 2; ++mt)
#pragma unroll
                        for (int r = 0; r < 4; ++r) {
                            int row = mt * 16 + quad * 4 + r;
                            dst[(h * 32 + row) * 72 + d] = (f16)(acc[mt][j][r] + bb[j]);
                        }
                }
            }
        }
    }
    __syncthreads();

    // --- Phase 2: wave hh (<6) computes scores + softmax -> P (aliases qL) ---
    const int hh = w;
    if (w < 6) {
        float4v s00 = vz, s01 = vz, s10 = vz, s11 = vz;
#pragma unroll
        for (int ks = 0; ks < 2; ++ks) {
            int c = ks * 32 + quad * 8;
            half8 aq0 = *(const half8*)&qL[(hh * 32 + lr) * 72 + c];
            half8 aq1 = *(const half8*)&qL[(hh * 32 + 16 + lr) * 72 + c];
            half8 bk0 = *(const half8*)&kL[(hh * 32 + lr) * 72 + c];
            half8 bk1 = *(const half8*)&kL[(hh * 32 + 16 + lr) * 72 + c];
            s00 = MFMA16(aq0, bk0, s00);
            s01 = MFMA16(aq0, bk1, s01);
            s10 = MFMA16(aq1, bk0, s10);
            s11 = MFMA16(aq1, bk1, s11);
        }
        f16* ph = qL + hh * 32 * 72;
#pragma unroll
        for (int mt = 0; mt < 2; ++mt) {
            float4v sv0 = mt ? s10 : s00;
            float4v sv1 = mt ? s11 : s01;
#pragma unroll
            for (int r = 0; r < 4; ++r) {
                float v0 = sv0[r], v1 = sv1[r];
                float m = fmaxf(v0, v1);
#pragma unroll
                for (int off = 1; off < 16; off <<= 1) m = fmaxf(m, __shfl_xor(m, off, 64));
                float e0 = __expf(v0 - m), e1 = __expf(v1 - m);
                float ss = e0 + e1;
#pragma unroll
                for (int off = 1; off < 16; off <<= 1) ss += __shfl_xor(ss, off, 64);
                float inv = 1.0f / ss;
                int row = mt * 16 + quad * 4 + r;
                ph[row * 40 + lr] = (f16)(e0 * inv);
                ph[row * 40 + 16 + lr] = (f16)(e1 * inv);
            }
        }
    }
    __syncthreads();

    // --- Phase 3: ctx = P @ V -> row-major scratch (reuses kL, [32][328]) ---
    f16* scratch = kL;
    for (int i = tid; i < 32 * 28; i += 512) {  // zero pad cols 300..327
        int row = i / 28, cc = 300 + (i - row * 28);
        scratch[row * 328 + cc] = (f16)0.f;
    }
    if (w < 6) {
        int h = hh;
        f16* ph = qL + hh * 32 * 72;
        half8 aw0 = *(const half8*)&ph[lr * 40 + quad * 8];
        half8 aw1 = *(const half8*)&ph[(16 + lr) * 40 + quad * 8];
        float4v c0[4], c1[4];
#pragma unroll
        for (int nt = 0; nt < 4; ++nt) { c0[nt] = vz; c1[nt] = vz; }
#pragma unroll
        for (int nt = 0; nt < 4; ++nt) {
            int rIdx = nt * 16 + lr;
            int idx = (hh * 64 + rIdx) * 32 + quad * 8;
            int byt = (idx * 2) ^ (((rIdx >> 2) & 3) << 4);
            half8 bvf = *(const half8*)((const char*)vT + byt);
            c0[nt] = MFMA16(aw0, bvf, c0[nt]);
            c1[nt] = MFMA16(aw1, bvf, c1[nt]);
        }
#pragma unroll
        for (int mt = 0; mt < 2; ++mt)
#pragma unroll
            for (int nt = 0; nt < 4; ++nt)
#pragma unroll
                for (int r = 0; r < 4; ++r) {
                    int d = nt * 16 + lr;
                    if (d < 50) {
                        int row = mt * 16 + quad * 4 + r;
                        float4v cv = mt ? c1[nt] : c0[nt];
                        scratch[row * 328 + h * 50 + d] = (f16)cv[r];
                    }
                }
    }

    // --- Preload P4's ks=0 B-frags + bva + qw BEFORE the barrier (latency hide) ---
    const int mtile = w >> 2, nsub = w & 3;  // 2 m-tiles x 4 n-groups, 5 ntiles each
    half8 pbf[5];
    float pbva[5], pqw[5];
#pragma unroll
    for (int i = 0; i < 5; ++i) {
        int n = (nsub * 5 + i) * 16 + lr;
        pbf[i] = *(const half8*)&wvaF[(((nsub * 5 + i) * 10) * 64 + lane) * 8];
        pbva[i] = bva[n];
        pqw[i] = (n < 300) ? qw[n] : 0.f;
    }
    __syncthreads();

    // --- Phase 4: va GEMM: y = ctx @ Wva^T + bva; a[l] = sum tanh(y)*qw ---
    {
        float4v vacc[5];
#pragma unroll
        for (int i = 0; i < 5; ++i) vacc[i] = vz;
        const int arow = (mtile * 16 + lr) * 328;
        {
            half8 a = *(const half8*)&scratch[arow + quad * 8];
#pragma unroll
            for (int i = 0; i < 5; ++i) vacc[i] = MFMA16(a, pbf[i], vacc[i]);
        }
#pragma unroll
        for (int ks = 1; ks < 10; ++ks) {
            half8 a = *(const half8*)&scratch[arow + ks * 32 + quad * 8];
#pragma unroll
            for (int i = 0; i < 5; ++i) {
                half8 bf = *(const half8*)&wvaF[((((nsub * 5 + i) * 10) + ks) * 64 + lane) * 8];
                vacc[i] = MFMA16(a, bf, vacc[i]);
            }
        }
        float ps[4] = {0.f, 0.f, 0.f, 0.f};
#pragma unroll
        for (int i = 0; i < 5; ++i) {
#pragma unroll
            for (int r = 0; r < 4; ++r) ps[r] += fast_tanh(vacc[i][r] + pbva[i]) * pqw[i];
        }
#pragma unroll
        for (int r = 0; r < 4; ++r)
#pragma unroll
            for (int off = 1; off < 16; off <<= 1) ps[r] += __shfl_xor(ps[r], off, 64);
        if (lr == 0) {
#pragma unroll
            for (int r = 0; r < 4; ++r) atomicAdd(&aL[mtile * 16 + quad * 4 + r], ps[r]);
        }
    }
    __syncthreads();

    // --- Phase 5+6 fused: every wave computes the 32-softmax redundantly,
    //     alpha broadcast via shfl (no LDS, no barrier, no single-wave phase) ---
    {
        float av = aL[lane & 31];
        float m5 = av;
#pragma unroll
        for (int off = 1; off < 32; off <<= 1) m5 = fmaxf(m5, __shfl_xor(m5, off, 32));
        float e5 = __expf(av - m5);
        float ss5 = e5;
#pragma unroll
        for (int off = 1; off < 32; off <<= 1) ss5 += __shfl_xor(ss5, off, 32);
        float al = e5 / ss5;  // lane (l&31) holds alpha[l&31]
        if (tid < 320) {
            int d = tid;
            float acc = 0.f;
#pragma unroll
            for (int l = 0; l < 32; ++l)
                acc += __shfl(al, l, 32) * (float)scratch[l * 328 + d];
            cbar[ib * 320 + d] = (f16)acc;
        }
    }
}

// ---------------- out = cbar @ Wo^T + bo, f32 [4096][300] ----------------
__global__ __launch_bounds__(512) void out_kernel(
    const f16* __restrict__ cbar, const f16* __restrict__ wo16F,
    const float* __restrict__ bo, float* __restrict__ out) {
    __shared__ __align__(16) f16 cA[32 * 328];
    const int mb = blockIdx.x, tid = threadIdx.x;  // 128 blocks, M=32
    const int w = tid >> 6, lane = tid & 63, lr = lane & 15, quad = lane >> 4;
    const int mh = w >> 2, nsub = w & 3;
    for (int i = tid; i < 1280; i += 512) {
        int row = i / 40, g = i - row * 40;
        *(half8*)&cA[row * 328 + g * 8] = *(const half8*)&cbar[(mb * 32 + row) * 320 + g * 8];
    }
    __syncthreads();
    const float4v vz = {0.f, 0.f, 0.f, 0.f};
    float4v acc[5];
#pragma unroll
    for (int i = 0; i < 5; ++i) acc[i] = vz;
#pragma unroll
    for (int ks = 0; ks < 10; ++ks) {
        half8 a = *(const half8*)&cA[(mh * 16 + lr) * 328 + ks * 32 + quad * 8];
#pragma unroll
        for (int i = 0; i < 5; ++i) {
            half8 bf = *(const half8*)&wo16F[((((nsub * 5 + i) * 10) + ks) * 64 + lane) * 8];
            acc[i] = MFMA16(a, bf, acc[i]);
        }
    }
#pragma unroll
    for (int i = 0; i < 5; ++i) {
        int n = (nsub * 5 + i) * 16 + lr;
        if (n < 300) {
            float bb = bo[n];
#pragma unroll
            for (int r = 0; r < 4; ++r)
                out[(mb * 32 + mh * 16 + quad * 4 + r) * 300 + n] = acc[i][r] + bb;
        }
    }
}

// ---------------- host launcher ----------------
extern "C" void kernel_launch(void* const* d_in, const int* in_sizes, int n_in,
                              void* d_out, int out_size, void* d_ws, size_t ws_size,
                              hipStream_t stream) {
    const int* title = (const int*)d_in[0];
    const float* emb = (const float*)d_in[1];
    const float* pos = (const float*)d_in[2];
    const float* Wq = (const float*)d_in[3];
    const float* bq = (const float*)d_in[4];
    const float* Wk = (const float*)d_in[5];
    const float* bk = (const float*)d_in[6];
    const float* Wv = (const float*)d_in[7];
    const float* bv = (const float*)d_in[8];
    const float* Wo = (const float*)d_in[9];
    const float* bo = (const float*)d_in[10];
    const float* Va = (const float*)d_in[11];
    const float* ba = (const float*)d_in[12];
    const float* qw = (const float*)d_in[13];
    char* ws = (char*)d_ws;
    float* out = (float*)d_out;

    f16* wqkvF = (f16*)(ws + WQKV_OFF);
    float* bqkv = (float*)(ws + BQKV_OFF);
    f16* wo16F = (f16*)(ws + WO_OFF);
    f16* wvaF = (f16*)(ws + WVA_OFF);
    float* bva = (float*)(ws + BVA_OFF);
    f16* cbar = (f16*)(ws + CBAR_OFF);
    f16* xF = (f16*)(ws + XF_OFF);

    repack1<<<1684, 256, 0, stream>>>(Wq, Wk, Wv, Wo, bq, bk, bv, wqkvF, wo16F, bqkv);
    repack2<<<400, 64, 0, stream>>>(Va, Wo, wvaF);
    repack3<<<1, 320, 0, stream>>>(Va, bo, ba, bva);
    gather_kernel<<<20480, 256, 0, stream>>>(title, emb, pos, xF);
    qkvattn_kernel<<<4096, 512, 0, stream>>>(xF, wqkvF, bqkv, wvaF, bva, qw, cbar);
    out_kernel<<<128, 512, 0, stream>>>(cbar, wo16F, bo, out);
}

// Round 3
// 431.159 us; speedup vs baseline: 1.0406x; 1.0353x over previous
//
#include <hip/hip_runtime.h>
#include <math.h>

typedef _Float16 f16;
typedef _Float16 half8 __attribute__((ext_vector_type(8)));
typedef _Float16 half4 __attribute__((ext_vector_type(4)));
typedef float float4v __attribute__((ext_vector_type(4)));
typedef int int4v __attribute__((ext_vector_type(4)));

#define MFMA16(a, b, c) __builtin_amdgcn_mfma_f32_16x16x32_f16((a), (b), (c), 0, 0, 0)

// problem: B=4096 L=32 V=50000 D=300 H=6 HD=50 ; K padded to 320
// Fragment-swizzled layout: element (n, k) of a [Nt*16][320] matrix lives at
//   F[((n>>4)*10 + (k>>5))*512 + (((k>>3)&3)*16 + (n&15))*8 + (k&7)]

// ---------------- ws layout (bytes) ----------------
#define WQKV_OFF 0u          // f16 frag-swizzled [64 ntiles] (q*rs | k | v rows, pads 0)
#define BQKV_OFF 655360u     // f32 [1024]
#define WO_OFF   659456u     // f16 frag-swizzled [20 ntiles] Wo
#define WVA_OFF  864256u     // f16 frag-swizzled [20 ntiles] Va@Wo
#define BVA_OFF  1069056u    // f32 [320]  Va@bo+ba (pads 0)
#define CBAR_OFF 1070336u    // f16 [4096][320] row-major

__device__ __forceinline__ float fast_tanh(float x) {
    float e = __expf(2.f * x);
    return 1.f - 2.f / (e + 1.f);
}

// ---------------- repack1: Wqkv + Wo -> frag-swizzled f16, bqkv ----------
__global__ void repack1(const float* __restrict__ Wq, const float* __restrict__ Wk,
                        const float* __restrict__ Wv, const float* __restrict__ Wo,
                        const float* __restrict__ bq, const float* __restrict__ bk,
                        const float* __restrict__ bv,
                        f16* __restrict__ wqkvF, f16* __restrict__ wo16F,
                        float* __restrict__ bqkv) {
    int idx = blockIdx.x * 256 + threadIdx.x;
    const float rs = 0.14142135623730951f;  // 1/sqrt(50)
    if (idx < 327680) {  // wqkvF: 64 ntiles
        int ntile = idx / 5120, rem = idx - ntile * 5120;
        int ks = rem / 512, r2 = rem - ks * 512;
        int lane = r2 >> 3, j = r2 & 7;
        int n = ntile * 16 + (lane & 15);
        int k = ks * 32 + (lane >> 4) * 8 + j;
        int g = n / 320, r = n - g * 320;
        float v = 0.f;
        if (r < 300 && k < 300) {
            if (g == 0) v = Wq[r * 300 + k] * rs;
            else if (g == 1) v = Wk[r * 300 + k];
            else if (g == 2) v = Wv[r * 300 + k];
        }
        wqkvF[idx] = (f16)v;
    } else if (idx < 430080) {  // wo16F: 20 ntiles
        int t = idx - 327680;
        int ntile = t / 5120, rem = t - ntile * 5120;
        int ks = rem / 512, r2 = rem - ks * 512;
        int lane = r2 >> 3, j = r2 & 7;
        int n = ntile * 16 + (lane & 15);
        int k = ks * 32 + (lane >> 4) * 8 + j;
        wo16F[t] = (f16)((n < 300 && k < 300) ? Wo[n * 300 + k] : 0.f);
    } else if (idx < 431104) {  // bqkv [1024]
        int n = idx - 430080;
        int g = n / 320, r = n - g * 320;
        float v = 0.f;
        if (r < 300) {
            if (g == 0) v = bq[r] * rs;
            else if (g == 1) v = bk[r];
            else if (g == 2) v = bv[r];
        }
        bqkv[n] = v;
    }
}

// ---------------- repack2: Wva = Va @ Wo -> frag-swizzled ----------------
__global__ void repack2(const float* __restrict__ Va, const float* __restrict__ Wo,
                        f16* __restrict__ wvaF) {
    int bt = blockIdx.x;  // 400 = 20*20
    int mt = bt / 20, nt = bt % 20;
    int lane = threadIdx.x & 63;
    int lr = lane & 15, quad = lane >> 4;
    float4v acc = {0.f, 0.f, 0.f, 0.f};
    int m = mt * 16 + lr;   // Wva row
    int nn = nt * 16 + lr;  // Wva col (= Wo output dim)
    for (int ks = 0; ks < 10; ++ks) {
        int c = ks * 32 + quad * 8;
        half8 af, bf;
#pragma unroll
        for (int j = 0; j < 8; ++j) {
            int cc = c + j;
            af[j] = (f16)((m < 300 && cc < 300) ? Va[m * 300 + cc] : 0.f);
            bf[j] = (f16)((nn < 300 && cc < 300) ? Wo[cc * 300 + nn] : 0.f);
        }
        acc = MFMA16(af, bf, acc);
    }
#pragma unroll
    for (int r = 0; r < 4; ++r) {
        int row = mt * 16 + quad * 4 + r;  // Wva row index (n of va GEMM)
        int col = nt * 16 + lr;            // Wva col index (k of va GEMM)
        int addr = ((row >> 4) * 10 + (col >> 5)) * 512 +
                   (((col >> 3) & 3) * 16 + (row & 15)) * 8 + (col & 7);
        wvaF[addr] = (f16)acc[r];
    }
}

// ---------------- repack3: bva = Va @ bo + ba (parallel, 320 blocks) -----
__global__ void repack3(const float* __restrict__ Va, const float* __restrict__ bo,
                        const float* __restrict__ ba, float* __restrict__ bva) {
    int j = blockIdx.x;      // 0..319
    int lane = threadIdx.x;  // 64
    float s = 0.f;
    if (j < 300) {
        for (int k = lane; k < 300; k += 64) s += Va[j * 300 + k] * bo[k];
    }
#pragma unroll
    for (int off = 1; off < 64; off <<= 1) s += __shfl_xor(s, off, 64);
    if (lane == 0) bva[j] = (j < 300) ? s + ba[j] : 0.f;
}

// ---- fused gather + QKV GEMM + attention + va + softmax + pool ----
// 1 item/block. LDS: qL/kL [6*32][72], vT [6*64][32] = 80,064 B -> 2 blocks/CU.
// P0 gathers emb[title]+pos directly into LDS (aliased over vT) in frag layout;
// the former gather kernel + 84MB xF HBM round-trip are eliminated.
// Barriers: 5 (post-P0, post-kloop(A reads done), post-P1, post-P2, post-P3, post-P4).
__global__ __launch_bounds__(512, 4) void qkvattn_kernel(
    const int* __restrict__ title, const float* __restrict__ emb,
    const float* __restrict__ pos,
    const f16* __restrict__ wqkvF, const float* __restrict__ bqkv,
    const f16* __restrict__ wvaF, const float* __restrict__ bva,
    const float* __restrict__ qw, f16* __restrict__ cbar) {
    __shared__ __align__(16) f16 qL[6 * 32 * 72];
    __shared__ __align__(16) f16 kL[6 * 32 * 72];
    __shared__ __align__(16) f16 vT[6 * 64 * 32];  // first 20480 B alias xA staging
    __shared__ float aL[32];
    const int ib = blockIdx.x, tid = threadIdx.x;
    const int w = tid >> 6, lane = tid & 63, lr = lane & 15, quad = lane >> 4;
    const float4v vz = {0.f, 0.f, 0.f, 0.f};
    const int4v z4 = {0, 0, 0, 0};
    f16* xA = vT;  // [20 fragblks][64 lanes][8] f16 = 20480 B

    // --- P0: gather x = emb[title]+pos into LDS frag layout (aliases vT) ---
    for (int u = tid; u < 1280; u += 512) {
        int fragblk = u >> 6, lu = u & 63;
        int mt = fragblk / 10, ks = fragblk - mt * 10;
        int row = mt * 16 + (lu & 15);        // l index 0..31
        int col = ks * 32 + (lu >> 4) * 8;
        int t = title[ib * 32 + row];
        half8 h;
        if (col + 8 <= 300) {
            float4v e0 = *(const float4v*)&emb[t * 300 + col];
            float4v e1 = *(const float4v*)&emb[t * 300 + col + 4];
            float4v p0 = *(const float4v*)&pos[row * 300 + col];
            float4v p1 = *(const float4v*)&pos[row * 300 + col + 4];
#pragma unroll
            for (int j = 0; j < 4; ++j) {
                h[j] = (f16)(e0[j] + p0[j]);
                h[4 + j] = (f16)(e1[j] + p1[j]);
            }
        } else {
#pragma unroll
            for (int j = 0; j < 8; ++j) {
                int cc = col + j;
                h[j] = (f16)((cc < 300) ? emb[t * 300 + cc] + pos[row * 300 + cc] : 0.f);
            }
        }
        *(half8*)&xA[u * 8] = h;
    }
    // qL/kL pad zeroing (cols 50..63) — disjoint from P1 epilogue writes
    for (int i = tid; i < 1344; i += 512) {  // 192 hrows x 7 dwords
        int hrow = i / 7, c = i - hrow * 7;
        ((int*)&qL[hrow * 72 + 50])[c] = 0;
        ((int*)&kL[hrow * 72 + 50])[c] = 0;
    }
    if (tid < 32) aL[tid] = 0.f;
    // hoist bqkv bias loads (global, independent of LDS)
    float bb[8];
#pragma unroll
    for (int j = 0; j < 8; ++j) bb[j] = bqkv[(w * 8 + j) * 16 + lr];
    __syncthreads();  // xA visible

    // --- Phase 1: QKV GEMM, M=32 (item ib), N=960 (60 real tiles), K=320 ---
    float4v acc[2][8];
#pragma unroll
    for (int mt = 0; mt < 2; ++mt)
#pragma unroll
        for (int j = 0; j < 8; ++j) acc[mt][j] = vz;
#pragma unroll
    for (int ks = 0; ks < 10; ++ks) {
        half8 a0 = *(const half8*)&xA[(ks * 64 + lane) * 8];
        half8 a1 = *(const half8*)&xA[((10 + ks) * 64 + lane) * 8];
#pragma unroll
        for (int j = 0; j < 8; ++j) {
            int tile = w * 8 + j;
            if (tile < 60) {  // skip pure-pad tiles 60..63 (wave-uniform)
                half8 bf = *(const half8*)&wqkvF[((tile * 10 + ks) * 64 + lane) * 8];
                acc[0][j] = MFMA16(a0, bf, acc[0][j]);
                acc[1][j] = MFMA16(a1, bf, acc[1][j]);
            }
        }
    }
    __syncthreads();  // all xA reads done; vT may now be overwritten

    // vT pad zeroing (rows d=50..63 per head)
    for (int i = tid; i < 336; i += 512) {
        int t = i >> 2, c4 = i & 3;
        int h = t / 14, d = 50 + (t - (t / 14) * 14);
        ((int4v*)&vT[(h * 64 + d) * 32])[c4] = z4;
    }
    // epilogue: scatter q/k/v into LDS (wi is wave-uniform per j: 8 | 20)
#pragma unroll
    for (int j = 0; j < 8; ++j) {
        int tile = w * 8 + j;
        int wi = tile / 20;
        int n = tile * 16 + lr;
        int cc = n - wi * 320;
        if (wi < 3 && cc < 300) {
            int h = cc / 50, d = cc - h * 50;
            if (wi == 2) {  // v: packed b64 write, XOR-swizzled on byte bits 4-5
#pragma unroll
                for (int mt = 0; mt < 2; ++mt) {
                    int row0 = mt * 16 + quad * 4;
                    half4 pk;
#pragma unroll
                    for (int r = 0; r < 4; ++r) pk[r] = (f16)(acc[mt][j][r] + bb[j]);
                    int idx = (h * 64 + d) * 32 + row0;
                    int byt = (idx * 2) ^ (((d >> 2) & 3) << 4);
                    *(half4*)((char*)vT + byt) = pk;
                }
            } else {
                f16* dst = (wi == 0) ? qL : kL;
#pragma unroll
                for (int mt = 0; mt < 2; ++mt)
#pragma unroll
                    for (int r = 0; r < 4; ++r) {
                        int row = mt * 16 + quad * 4 + r;
                        dst[(h * 32 + row) * 72 + d] = (f16)(acc[mt][j][r] + bb[j]);
                    }
            }
        }
    }
    __syncthreads();

    // --- Phase 2: wave hh (<6) computes scores + softmax -> P (aliases qL) ---
    const int hh = w;
    if (w < 6) {
        float4v s00 = vz, s01 = vz, s10 = vz, s11 = vz;
#pragma unroll
        for (int ks = 0; ks < 2; ++ks) {
            int c = ks * 32 + quad * 8;
            half8 aq0 = *(const half8*)&qL[(hh * 32 + lr) * 72 + c];
            half8 aq1 = *(const half8*)&qL[(hh * 32 + 16 + lr) * 72 + c];
            half8 bk0 = *(const half8*)&kL[(hh * 32 + lr) * 72 + c];
            half8 bk1 = *(const half8*)&kL[(hh * 32 + 16 + lr) * 72 + c];
            s00 = MFMA16(aq0, bk0, s00);
            s01 = MFMA16(aq0, bk1, s01);
            s10 = MFMA16(aq1, bk0, s10);
            s11 = MFMA16(aq1, bk1, s11);
        }
        f16* ph = qL + hh * 32 * 72;
#pragma unroll
        for (int mt = 0; mt < 2; ++mt) {
            float4v sv0 = mt ? s10 : s00;
            float4v sv1 = mt ? s11 : s01;
#pragma unroll
            for (int r = 0; r < 4; ++r) {
                float v0 = sv0[r], v1 = sv1[r];
                float m = fmaxf(v0, v1);
#pragma unroll
                for (int off = 1; off < 16; off <<= 1) m = fmaxf(m, __shfl_xor(m, off, 64));
                float e0 = __expf(v0 - m), e1 = __expf(v1 - m);
                float ss = e0 + e1;
#pragma unroll
                for (int off = 1; off < 16; off <<= 1) ss += __shfl_xor(ss, off, 64);
                float inv = 1.0f / ss;
                int row = mt * 16 + quad * 4 + r;
                ph[row * 40 + lr] = (f16)(e0 * inv);
                ph[row * 40 + 16 + lr] = (f16)(e1 * inv);
            }
        }
    }
    __syncthreads();

    // --- Phase 3: ctx = P @ V -> row-major scratch (reuses kL, [32][328]) ---
    f16* scratch = kL;
    for (int i = tid; i < 32 * 28; i += 512) {  // zero pad cols 300..327
        int row = i / 28, cc = 300 + (i - row * 28);
        scratch[row * 328 + cc] = (f16)0.f;
    }
    if (w < 6) {
        int h = hh;
        f16* ph = qL + hh * 32 * 72;
        half8 aw0 = *(const half8*)&ph[lr * 40 + quad * 8];
        half8 aw1 = *(const half8*)&ph[(16 + lr) * 40 + quad * 8];
        float4v c0[4], c1[4];
#pragma unroll
        for (int nt = 0; nt < 4; ++nt) { c0[nt] = vz; c1[nt] = vz; }
#pragma unroll
        for (int nt = 0; nt < 4; ++nt) {
            int rIdx = nt * 16 + lr;
            int idx = (hh * 64 + rIdx) * 32 + quad * 8;
            int byt = (idx * 2) ^ (((rIdx >> 2) & 3) << 4);
            half8 bvf = *(const half8*)((const char*)vT + byt);
            c0[nt] = MFMA16(aw0, bvf, c0[nt]);
            c1[nt] = MFMA16(aw1, bvf, c1[nt]);
        }
#pragma unroll
        for (int mt = 0; mt < 2; ++mt)
#pragma unroll
            for (int nt = 0; nt < 4; ++nt)
#pragma unroll
                for (int r = 0; r < 4; ++r) {
                    int d = nt * 16 + lr;
                    if (d < 50) {
                        int row = mt * 16 + quad * 4 + r;
                        float4v cv = mt ? c1[nt] : c0[nt];
                        scratch[row * 328 + h * 50 + d] = (f16)cv[r];
                    }
                }
    }

    // --- Preload P4's ks=0 B-frags + bva + qw BEFORE the barrier (latency hide) ---
    const int mtile = w >> 2, nsub = w & 3;  // 2 m-tiles x 4 n-groups, 5 ntiles each
    half8 pbf[5];
    float pbva[5], pqw[5];
#pragma unroll
    for (int i = 0; i < 5; ++i) {
        int n = (nsub * 5 + i) * 16 + lr;
        pbf[i] = *(const half8*)&wvaF[(((nsub * 5 + i) * 10) * 64 + lane) * 8];
        pbva[i] = bva[n];
        pqw[i] = (n < 300) ? qw[n] : 0.f;
    }
    __syncthreads();

    // --- Phase 4: va GEMM: y = ctx @ Wva^T + bva; a[l] = sum tanh(y)*qw ---
    {
        float4v vacc[5];
#pragma unroll
        for (int i = 0; i < 5; ++i) vacc[i] = vz;
        const int arow = (mtile * 16 + lr) * 328;
        {
            half8 a = *(const half8*)&scratch[arow + quad * 8];
#pragma unroll
            for (int i = 0; i < 5; ++i) vacc[i] = MFMA16(a, pbf[i], vacc[i]);
        }
#pragma unroll
        for (int ks = 1; ks < 10; ++ks) {
            half8 a = *(const half8*)&scratch[arow + ks * 32 + quad * 8];
#pragma unroll
            for (int i = 0; i < 5; ++i) {
                half8 bf = *(const half8*)&wvaF[((((nsub * 5 + i) * 10) + ks) * 64 + lane) * 8];
                vacc[i] = MFMA16(a, bf, vacc[i]);
            }
        }
        float ps[4] = {0.f, 0.f, 0.f, 0.f};
#pragma unroll
        for (int i = 0; i < 5; ++i) {
#pragma unroll
            for (int r = 0; r < 4; ++r) ps[r] += fast_tanh(vacc[i][r] + pbva[i]) * pqw[i];
        }
#pragma unroll
        for (int r = 0; r < 4; ++r)
#pragma unroll
            for (int off = 1; off < 16; off <<= 1) ps[r] += __shfl_xor(ps[r], off, 64);
        if (lr == 0) {
#pragma unroll
            for (int r = 0; r < 4; ++r) atomicAdd(&aL[mtile * 16 + quad * 4 + r], ps[r]);
        }
    }
    __syncthreads();

    // --- Phase 5+6 fused: redundant 32-softmax per wave, alpha via shfl ---
    {
        float av = aL[lane & 31];
        float m5 = av;
#pragma unroll
        for (int off = 1; off < 32; off <<= 1) m5 = fmaxf(m5, __shfl_xor(m5, off, 32));
        float e5 = __expf(av - m5);
        float ss5 = e5;
#pragma unroll
        for (int off = 1; off < 32; off <<= 1) ss5 += __shfl_xor(ss5, off, 32);
        float al = e5 / ss5;  // lane (l&31) holds alpha[l&31]
        if (tid < 320) {
            int d = tid;
            float acc6 = 0.f;
#pragma unroll
            for (int l = 0; l < 32; ++l)
                acc6 += __shfl(al, l, 32) * (float)scratch[l * 328 + d];
            cbar[ib * 320 + d] = (f16)acc6;
        }
    }
}

// ---------------- out = cbar @ Wo^T + bo, f32 [4096][300] ----------------
__global__ __launch_bounds__(512) void out_kernel(
    const f16* __restrict__ cbar, const f16* __restrict__ wo16F,
    const float* __restrict__ bo, float* __restrict__ out) {
    __shared__ __align__(16) f16 cA[32 * 328];
    const int mb = blockIdx.x, tid = threadIdx.x;  // 128 blocks, M=32
    const int w = tid >> 6, lane = tid & 63, lr = lane & 15, quad = lane >> 4;
    const int mh = w >> 2, nsub = w & 3;
    for (int i = tid; i < 1280; i += 512) {
        int row = i / 40, g = i - row * 40;
        *(half8*)&cA[row * 328 + g * 8] = *(const half8*)&cbar[(mb * 32 + row) * 320 + g * 8];
    }
    __syncthreads();
    const float4v vz = {0.f, 0.f, 0.f, 0.f};
    float4v acc[5];
#pragma unroll
    for (int i = 0; i < 5; ++i) acc[i] = vz;
#pragma unroll
    for (int ks = 0; ks < 10; ++ks) {
        half8 a = *(const half8*)&cA[(mh * 16 + lr) * 328 + ks * 32 + quad * 8];
#pragma unroll
        for (int i = 0; i < 5; ++i) {
            half8 bf = *(const half8*)&wo16F[((((nsub * 5 + i) * 10) + ks) * 64 + lane) * 8];
            acc[i] = MFMA16(a, bf, acc[i]);
        }
    }
#pragma unroll
    for (int i = 0; i < 5; ++i) {
        int n = (nsub * 5 + i) * 16 + lr;
        if (n < 300) {
            float bb = bo[n];
#pragma unroll
            for (int r = 0; r < 4; ++r)
                out[(mb * 32 + mh * 16 + quad * 4 + r) * 300 + n] = acc[i][r] + bb;
        }
    }
}

// ---------------- host launcher ----------------
extern "C" void kernel_launch(void* const* d_in, const int* in_sizes, int n_in,
                              void* d_out, int out_size, void* d_ws, size_t ws_size,
                              hipStream_t stream) {
    const int* title = (const int*)d_in[0];
    const float* emb = (const float*)d_in[1];
    const float* pos = (const float*)d_in[2];
    const float* Wq = (const float*)d_in[3];
    const float* bq = (const float*)d_in[4];
    const float* Wk = (const float*)d_in[5];
    const float* bk = (const float*)d_in[6];
    const float* Wv = (const float*)d_in[7];
    const float* bv = (const float*)d_in[8];
    const float* Wo = (const float*)d_in[9];
    const float* bo = (const float*)d_in[10];
    const float* Va = (const float*)d_in[11];
    const float* ba = (const float*)d_in[12];
    const float* qw = (const float*)d_in[13];
    char* ws = (char*)d_ws;
    float* out = (float*)d_out;

    f16* wqkvF = (f16*)(ws + WQKV_OFF);
    float* bqkv = (float*)(ws + BQKV_OFF);
    f16* wo16F = (f16*)(ws + WO_OFF);
    f16* wvaF = (f16*)(ws + WVA_OFF);
    float* bva = (float*)(ws + BVA_OFF);
    f16* cbar = (f16*)(ws + CBAR_OFF);

    repack1<<<1684, 256, 0, stream>>>(Wq, Wk, Wv, Wo, bq, bk, bv, wqkvF, wo16F, bqkv);
    repack2<<<400, 64, 0, stream>>>(Va, Wo, wvaF);
    repack3<<<320, 64, 0, stream>>>(Va, bo, ba, bva);
    qkvattn_kernel<<<4096, 512, 0, stream>>>(title, emb, pos, wqkvF, bqkv, wvaF, bva, qw, cbar);
    out_kernel<<<128, 512, 0, stream>>>(cbar, wo16F, bo, out);
}